// Round 7
// baseline (393.991 us; speedup 1.0000x reference)
//
#include <hip/hip_runtime.h>
#include <stdint.h>

// ---------------------------------------------------------------------------
// DynamicConv (CondConv x2 + PReLU + self-routing + 1x1 out), MI355X gfx950
// R7: fn=8 wave tiles (384 B/MFMA), transposed [u][pix] unit layouts
//     (conflict-free by construction), per-s A dbuf via global_load_lds,
//     T14 reg-staged B for conv2, 8-row 512-thr blocks (2 waves/SIMD).
// ---------------------------------------------------------------------------

typedef _Float16 f16_t;
typedef _Float16 f16x8 __attribute__((ext_vector_type(8)));
typedef _Float16 f16x4 __attribute__((ext_vector_type(4)));
typedef float    f32x4 __attribute__((ext_vector_type(4)));

#define B_   8
#define R_   4
#define C_   64
#define C2_  128
#define H_   128
#define W_   128
#define E_   8
#define RF_  256
#define HP_  130
#define WP_  130
// unit = 8 f16 = 16 B. xbt row = 8u*130pix = 1040 units; xct row = 16u*130 = 2080.

__device__ __forceinline__ f32x4 mfma16(f16x8 a, f16x8 b, f32x4 c) {
  return __builtin_amdgcn_mfma_f32_16x16x32_f16(a, b, c, 0, 0, 0);
}

// async global->LDS, 16B per lane; dest wave-linear (base + lane*16)
__device__ __forceinline__ void gl16(const f16_t* g, f16_t* l) {
  __builtin_amdgcn_global_load_lds(
      (const __attribute__((address_space(1))) unsigned int*)(const void*)g,
      (__attribute__((address_space(3))) unsigned int*)(void*)l, 16, 0, 0);
}

// ---------- routing weights + zero pooled[4][B][C2] ----------
__global__ void k_rw(const float* __restrict__ routing, const float* __restrict__ rW,
                     const float* __restrict__ rB, float* __restrict__ rw,
                     float* __restrict__ pooled4) {
  int t = threadIdx.x;                 // 256 = R*B*E
  #pragma unroll
  for (int i = 0; i < 16; ++i) pooled4[i*256 + t] = 0.f;
  int e = t & 7, b = (t >> 3) & 7, r = t >> 6;
  float acc = rB[e];
  for (int f = 0; f < RF_; ++f)
    acc += routing[(b*R_ + r)*RF_ + f] * rW[f*E_ + e];
  rw[(r*B_ + b)*E_ + e] = 1.0f / (1.0f + __expf(-acc));
}

// ---------- zero guard rows/cols of xbt and xct (unit-granular) ----------
__global__ void k_zero(f16_t* __restrict__ xbt, f16_t* __restrict__ xct,
                       size_t xsu) {   // xsu = per-r xct stride in units
  const f16x8 z = {0,0,0,0,0,0,0,0};
  int t = blockIdx.x*256 + threadIdx.x;
  if (t < 16640) {                         // xbt guard rows: 8b*2rs*1040u
    int un = t % 1040, q = t / 1040;
    int rs = q & 1, b = q >> 1;
    *(f16x8*)&xbt[((size_t)(b*HP_ + rs*129)*1040 + un)*8] = z;
    return;
  }
  t -= 16640;
  if (t < 133120) {                        // xct guard rows: 4r*8b*2rs*2080u
    int un = t % 2080, q = t / 2080;
    int rs = q & 1, b = (q >> 1) & 7, r = q >> 4;
    *(f16x8*)&xct[((size_t)r*xsu + (size_t)(b*HP_ + rs*129)*2080 + un)*8] = z;
    return;
  }
  t -= 133120;
  if (t < 131072) {                        // xct guard cols: 4r*8b*128row*16u*2cs
    int cs = t & 1, u = (t >> 1) & 15, prow = ((t >> 5) & 127) + 1;
    int b = (t >> 12) & 7, r = t >> 15;
    *(f16x8*)&xct[((size_t)r*xsu + (size_t)(b*HP_ + prow)*2080 + u*130 + cs*129)*8] = z;
  }
}

// ---------- x: NCHW f32 -> xbt [b][prow][u8][pix130] f16 ----------
__global__ void k_xt(const float* __restrict__ x, f16_t* __restrict__ xbt) {
  int wh = blockIdx.x, h = blockIdx.y, b = blockIdx.z;
  int t = threadIdx.x;
  int w0 = wh * 64;
  __shared__ float tile[64][65];
  #pragma unroll
  for (int rep = 0; rep < 16; ++rep) {
    int idx = rep*256 + t;
    int c = idx >> 6, w = idx & 63;
    tile[c][w] = x[((size_t)(b*C_ + c)*H_ + h)*W_ + w0 + w];
  }
  __syncthreads();
  size_t rowb = (size_t)(b*HP_ + h + 1)*1040;
  #pragma unroll
  for (int rep = 0; rep < 16; ++rep) {
    int idx = rep*256 + t;
    int w = idx >> 6, c = idx & 63;
    xbt[(rowb + (c>>3)*130 + (w0 + w + 1))*8 + (c & 7)] = (f16_t)tile[c][w];
  }
  if (t < 64) {
    int u = t >> 3, c7 = t & 7;
    int gp = (wh == 0) ? 0 : 129;
    xbt[(rowb + u*130 + gp)*8 + c7] = (f16_t)0.0f;
  }
}

// ---------- mix1: w1m [rb][coh][cb][s][u2 4][co6 64] units ----------
__global__ void k_mix1(const float* __restrict__ rw, const float* __restrict__ W1,
                       f16_t* __restrict__ w1m) {
  int gid = blockIdx.x*256 + threadIdx.x;    // 589824 total
  int cq4 = gid & 15;                        // ch quad: ch = cq4*4 .. +3
  int s   = (gid >> 4) % 9;
  int t2  = (gid >> 4) / 9;
  int co  = t2 & 127;
  int rb  = t2 >> 7;                         // 0..31
  float o0=0.f,o1=0.f,o2=0.f,o3=0.f;
  #pragma unroll
  for (int e = 0; e < E_; ++e) {
    float rv = rw[rb*E_ + e];
    const float* wp = W1 + (size_t)((e*C2_ + co)*C_ + cq4*4)*9 + s;
    o0 += rv*wp[0]; o1 += rv*wp[9]; o2 += rv*wp[18]; o3 += rv*wp[27];
  }
  f16x4 pk; pk[0]=(f16_t)o0; pk[1]=(f16_t)o1; pk[2]=(f16_t)o2; pk[3]=(f16_t)o3;
  int coh = co >> 6, co6 = co & 63;
  int cb = cq4 >> 3, u2 = (cq4 >> 1) & 3, half = cq4 & 1;
  size_t unit = ((size_t)(((rb*2 + coh)*2 + cb)*9 + s)*4 + u2)*64 + co6;
  *(f16x4*)&w1m[unit*8 + half*4] = pk;
}

// ---------- mix2 (+inline srw): w2m [r][b][cb4][s][u2 4][co 64] units -------
__global__ void k_mix2(const float* __restrict__ pooled, const float* __restrict__ srW,
                       const float* __restrict__ srb, const float* __restrict__ W2,
                       f16_t* __restrict__ w2m, int r0) {
  const int r = r0 + blockIdx.y;
  const float* pooled_r = pooled + (size_t)r*B_*C2_;
  f16_t* w2m_r = w2m + (size_t)r*73728*8;
  __shared__ float sw[64];
  int t = threadIdx.x;
  if (t < 64) {
    int b = t >> 3, e = t & 7;
    float acc = srb[e];
    for (int c = 0; c < C2_; ++c)
      acc += pooled_r[b*C2_ + c] * (1.0f/16384.0f) * srW[c*E_ + e];
    sw[t] = acc;
  }
  __syncthreads();
  int gid = blockIdx.x*256 + t;              // 147456 total
  int c2q = gid & 31;                        // ch quad
  int s   = (gid >> 5) % 9;
  int t2  = (gid >> 5) / 9;
  int co  = t2 & 63;
  int b   = t2 >> 6;
  float o0=0.f,o1=0.f,o2=0.f,o3=0.f;
  #pragma unroll
  for (int e = 0; e < E_; ++e) {
    float rv = sw[b*E_ + e];
    const float* wp = W2 + (size_t)((e*C_ + co)*C2_ + c2q*4)*9 + s;
    o0 += rv*wp[0]; o1 += rv*wp[9]; o2 += rv*wp[18]; o3 += rv*wp[27];
  }
  f16x4 pk; pk[0]=(f16_t)o0; pk[1]=(f16_t)o1; pk[2]=(f16_t)o2; pk[3]=(f16_t)o3;
  int cb = c2q >> 3, u2 = (c2q >> 1) & 3, half = c2q & 1;
  size_t unit = ((size_t)((b*4 + cb)*9 + s)*4 + u2)*64 + co;
  *(f16x4*)&w2m_r[unit*8 + half*4] = pk;
}

// ---------- conv1: block (b, coh, 8 rows, r): 64co x (8x128)pix x 576K -------
__global__ __launch_bounds__(512, 2) void k_conv1(
    const f16_t* __restrict__ xbt, const f16_t* __restrict__ w1m,
    const float* __restrict__ pa, f16_t* __restrict__ xct, size_t xsu,
    float* __restrict__ pooled, int r0)
{
  const int bx = blockIdx.x;
  const int b = bx & 7, h0 = (bx >> 3) << 3;     // b low bits -> XCD pin
  const int coh = blockIdx.y;
  const int r = r0 + blockIdx.z;
  const int tid = threadIdx.x;
  const int lane = tid & 63;
  const int wid = tid >> 6;                      // = output row within block
  const int l15 = lane & 15, l4 = lane >> 4;
  __shared__ __align__(16) f16_t lB[5200*8];     // [10 rows][4 u][130 pix] = 83,200 B
  __shared__ __align__(16) f16_t lA[2][256*8];   // [4 u][64 co] dbuf       =  8,192 B

  f32x4 acc[4][8];
  #pragma unroll
  for (int i=0;i<4;++i)
    #pragma unroll
    for (int j=0;j<8;++j) acc[i][j] = (f32x4){0.f,0.f,0.f,0.f};

  const f16_t* xsrc  = xbt + ((size_t)(b*HP_ + h0))*1040*8;
  const f16_t* wbase = w1m + ((size_t)((r*B_ + b)*2 + coh))*2*9*256*8;
  f16_t* xct_r = xct + (size_t)blockIdx.z*xsu*8;

  // prologue: B(cb0) + A(cb0,s0)
  #pragma unroll
  for (int k = 0; k < 10; ++k) {
    int u = tid + 512*k; int lr = u/520, j = u - lr*520;
    gl16(xsrc + ((size_t)(lr*1040 + j))*8, &lB[u*8]);
  }
  if (tid < 80) {
    int u = 5120 + tid; int lr = u/520, j = u - lr*520;
    gl16(xsrc + ((size_t)(lr*1040 + j))*8, &lB[u*8]);
  }
  if (tid < 256) gl16(wbase + (size_t)tid*8, &lA[0][tid*8]);
  __syncthreads();

  int cur = 0;
  for (int cb = 0; cb < 2; ++cb) {
    if (cb) {   // re-stage B for ch-half 1 (previous barrier freed lB)
      #pragma unroll
      for (int k = 0; k < 10; ++k) {
        int u = tid + 512*k; int lr = u/520, j = u - lr*520;
        gl16(xsrc + ((size_t)(lr*1040 + 520 + j))*8, &lB[u*8]);
      }
      if (tid < 80) {
        int u = 5120 + tid; int lr = u/520, j = u - lr*520;
        gl16(xsrc + ((size_t)(lr*1040 + 520 + j))*8, &lB[u*8]);
      }
      __syncthreads();
    }
    #pragma unroll
    for (int s = 0; s < 9; ++s) {
      const int nc = (s < 8) ? cb : cb + 1;
      const int ns = (s < 8) ? s + 1 : 0;
      if (nc < 2 && tid < 256)
        gl16(wbase + ((size_t)((nc*9 + ns)*256 + tid))*8, &lA[cur^1][tid*8]);
      const int dh = s / 3, dw = s % 3;
      f16x8 af[4], bf[8];
      #pragma unroll
      for (int fm = 0; fm < 4; ++fm)
        af[fm] = *(const f16x8*)&lA[cur][(l4*64 + fm*16 + l15)*8];
      #pragma unroll
      for (int fn = 0; fn < 8; ++fn)
        bf[fn] = *(const f16x8*)&lB[((wid + dh)*520 + l4*130 + fn*16 + l15 + dw)*8];
      __builtin_amdgcn_s_setprio(1);
      #pragma unroll
      for (int fm = 0; fm < 4; ++fm)
        #pragma unroll
        for (int fn = 0; fn < 8; ++fn)
          acc[fm][fn] = mfma16(af[fm], bf[fn], acc[fm][fn]);
      __builtin_amdgcn_s_setprio(0);
      __syncthreads();
      cur ^= 1;
    }
  }

  // epilogue: PReLU + pooled + transposed coalesced xct store
  const float a = pa[0];
  float ps[4][4];
  #pragma unroll
  for (int fm=0;fm<4;++fm)
    #pragma unroll
    for (int j=0;j<4;++j) ps[fm][j] = 0.f;
  #pragma unroll
  for (int fm = 0; fm < 4; ++fm)
    #pragma unroll
    for (int fn = 0; fn < 8; ++fn)
      #pragma unroll
      for (int j = 0; j < 4; ++j) {
        float v = acc[fm][fn][j];
        v = (v >= 0.f) ? v : a*v;
        acc[fm][fn][j] = v;
        ps[fm][j] += v;
      }
  #pragma unroll
  for (int fm = 0; fm < 4; ++fm)
    #pragma unroll
    for (int j = 0; j < 4; ++j) {
      float s = ps[fm][j];
      s += __shfl_xor(s, 1, 64);
      s += __shfl_xor(s, 2, 64);
      s += __shfl_xor(s, 4, 64);
      s += __shfl_xor(s, 8, 64);
      if (l15 == 0)
        atomicAdd(&pooled[(size_t)r*B_*C2_ + b*C2_ + coh*64 + fm*16 + l4*4 + j], s);
    }
  // 4 rounds x 2 rows: acc -> LDS [rr][pix][co^swz] -> contiguous global units
  #pragma unroll
  for (int t4 = 0; t4 < 4; ++t4) {
    if ((wid >> 1) == t4) {
      const int rr = wid & 1;
      #pragma unroll
      for (int fm = 0; fm < 4; ++fm)
        #pragma unroll
        for (int fn = 0; fn < 8; ++fn) {
          f16x4 pk;
          #pragma unroll
          for (int j = 0; j < 4; ++j) pk[j] = (f16_t)acc[fm][fn][j];
          int pix = fn*16 + l15;
          int cof = (fm*16 + l4*4) ^ ((pix & 7) << 3);
          *(f16x4*)&lB[(rr*128 + pix)*64 + cof] = pk;
        }
    }
    __syncthreads();
    #pragma unroll
    for (int k = 0; k < 4; ++k) {
      int idx = tid + 512*k;               // 2048 units
      int rr = idx >> 10, u = (idx >> 7) & 7, pix = idx & 127;
      f16x8 v = *(const f16x8*)&lB[(rr*128 + pix)*64 + ((u ^ (pix & 7)) << 3)];
      size_t gu = (size_t)(b*HP_ + h0 + 2*t4 + rr + 1)*2080 + (coh*8 + u)*130 + pix + 1;
      *(f16x8*)(xct_r + gu*8) = v;
    }
    __syncthreads();
  }
}

// ---------- conv2 + PReLU + 1x1 Wout: block (b, 8 rows, r): 64 x 1024 x 1152
__global__ __launch_bounds__(512, 2) void k_conv2(
    const f16_t* __restrict__ xct, size_t xsu,
    const f16_t* __restrict__ w2m,
    const float* __restrict__ pa, const float* __restrict__ Wout,
    const float* __restrict__ bout, float* __restrict__ out, int r0)
{
  const int bx = blockIdx.x;
  const int b = bx & 7, h0 = (bx >> 3) << 3;
  const int r = r0 + blockIdx.y;
  const int tid = threadIdx.x;
  const int lane = tid & 63;
  const int wid = tid >> 6;
  const int l15 = lane & 15, l4 = lane >> 4;
  __shared__ __align__(16) f16_t lB[5200*8];
  __shared__ __align__(16) f16_t lA[2][256*8];

  f32x4 acc[4][8];
  #pragma unroll
  for (int i=0;i<4;++i)
    #pragma unroll
    for (int j=0;j<8;++j) acc[i][j] = (f32x4){0.f,0.f,0.f,0.f};

  const f16_t* xsrc  = xct + ((size_t)blockIdx.y*xsu + (size_t)(b*HP_ + h0)*2080)*8;
  const f16_t* wbase = w2m + ((size_t)r*73728 + (size_t)b*4*9*256)*8;

  // prologue: B(cb0) via DMA + A(cb0,s0)
  #pragma unroll
  for (int k = 0; k < 10; ++k) {
    int u = tid + 512*k; int lr = u/520, j = u - lr*520;
    gl16(xsrc + ((size_t)(lr*2080 + j))*8, &lB[u*8]);
  }
  if (tid < 80) {
    int u = 5120 + tid; int lr = u/520, j = u - lr*520;
    gl16(xsrc + ((size_t)(lr*2080 + j))*8, &lB[u*8]);
  }
  if (tid < 256) gl16(wbase + (size_t)tid*8, &lA[0][tid*8]);
  __syncthreads();

  int cur = 0;
  uint4 br[11];
  for (int cb = 0; cb < 4; ++cb) {
    if (cb < 3) {   // T14: issue next-B loads now, write at cb-end barrier
      #pragma unroll
      for (int k = 0; k < 10; ++k) {
        int u = tid + 512*k; int lr = u/520, j = u - lr*520;
        br[k] = *(const uint4*)(xsrc + ((size_t)(lr*2080 + (cb+1)*520 + j))*8);
      }
      if (tid < 80) {
        int u = 5120 + tid; int lr = u/520, j = u - lr*520;
        br[10] = *(const uint4*)(xsrc + ((size_t)(lr*2080 + (cb+1)*520 + j))*8);
      }
    }
    #pragma unroll
    for (int s = 0; s < 9; ++s) {
      const int nc = (s < 8) ? cb : cb + 1;
      const int ns = (s < 8) ? s + 1 : 0;
      if (nc < 4 && tid < 256)
        gl16(wbase + ((size_t)((nc*9 + ns)*256 + tid))*8, &lA[cur^1][tid*8]);
      const int dh = s / 3, dw = s % 3;
      f16x8 af[4], bf[8];
      #pragma unroll
      for (int fm = 0; fm < 4; ++fm)
        af[fm] = *(const f16x8*)&lA[cur][(l4*64 + fm*16 + l15)*8];
      #pragma unroll
      for (int fn = 0; fn < 8; ++fn)
        bf[fn] = *(const f16x8*)&lB[((wid + dh)*520 + l4*130 + fn*16 + l15 + dw)*8];
      __builtin_amdgcn_s_setprio(1);
      #pragma unroll
      for (int fm = 0; fm < 4; ++fm)
        #pragma unroll
        for (int fn = 0; fn < 8; ++fn)
          acc[fm][fn] = mfma16(af[fm], bf[fn], acc[fm][fn]);
      __builtin_amdgcn_s_setprio(0);
      __syncthreads();
      cur ^= 1;
    }
    if (cb < 3) {
      #pragma unroll
      for (int k = 0; k < 10; ++k) { int u = tid + 512*k; *(uint4*)&lB[u*8] = br[k]; }
      if (tid < 80)                { int u = 5120 + tid;  *(uint4*)&lB[u*8] = br[10]; }
      __syncthreads();
    }
  }

  // epilogue: PReLU + Wout reduce -> out[b][r][h0+wid][*]
  const float a  = pa[0];
  const float bo = bout[0];
  float wr_[4][4];
  #pragma unroll
  for (int fm = 0; fm < 4; ++fm)
    #pragma unroll
    for (int j = 0; j < 4; ++j)
      wr_[fm][j] = Wout[fm*16 + l4*4 + j];
  float* orow = out + ((size_t)((b*R_ + r)*H_ + h0 + wid))*W_;
  #pragma unroll
  for (int fn = 0; fn < 8; ++fn) {
    float s = 0.f;
    #pragma unroll
    for (int fm = 0; fm < 4; ++fm)
      #pragma unroll
      for (int j = 0; j < 4; ++j) {
        float v = acc[fm][fn][j];
        v = (v >= 0.f) ? v : a*v;
        s += wr_[fm][j]*v;
      }
    s += __shfl_xor(s, 16, 64);
    s += __shfl_xor(s, 32, 64);
    if (lane < 16)
      orow[fn*16 + lane] = s + bo;
  }
}

// ---------------------------------------------------------------------------
extern "C" void kernel_launch(void* const* d_in, const int* in_sizes, int n_in,
                              void* d_out, int out_size, void* d_ws, size_t ws_size,
                              hipStream_t stream) {
  (void)in_sizes; (void)n_in; (void)out_size;
  const float* x       = (const float*)d_in[0];
  const float* routing = (const float*)d_in[1];
  const float* rW      = (const float*)d_in[2];
  const float* rB      = (const float*)d_in[3];
  const float* W1      = (const float*)d_in[4];
  const float* pa      = (const float*)d_in[5];
  const float* W2      = (const float*)d_in[6];
  const float* srW     = (const float*)d_in[7];
  const float* srb     = (const float*)d_in[8];
  const float* Wout    = (const float*)d_in[9];
  const float* bout    = (const float*)d_in[10];
  float* out = (float*)d_out;

  const size_t xbt_b = (size_t)B_*HP_*1040*16;       // 17,305,600
  const size_t w1m_b = (size_t)294912*16;            //  4,718,592
  const size_t xct_u = (size_t)B_*HP_*2080;          // units per r copy
  const size_t xct_b = xct_u*16;                     // 34,611,200
  const size_t w2m_b = (size_t)4*73728*16;           //  4,718,592
  const size_t need_fused = xbt_b + w1m_b + 4*xct_b + w2m_b + 32768;
  const bool fused = (ws_size >= need_fused);
  const int ncopies = fused ? 4 : 1;
  const size_t xsu = fused ? xct_u : 0;

  char* ws = (char*)d_ws;
  size_t off = 0;
  f16_t* xbt = (f16_t*)(ws + off); off += xbt_b;
  f16_t* w1m = (f16_t*)(ws + off); off += w1m_b;
  f16_t* xct = (f16_t*)(ws + off); off += xct_b*ncopies;
  f16_t* w2m = (f16_t*)(ws + off); off += w2m_b;
  float* rw     = (float*)(ws + off); off += (size_t)R_*B_*E_*4;
  float* pooled = (float*)(ws + off); off += (size_t)R_*B_*C2_*4;

  k_rw  <<<1, 256, 0, stream>>>(routing, rW, rB, rw, pooled);
  k_zero<<<1097, 256, 0, stream>>>(xbt, xct, xsu);
  k_xt  <<<dim3(2, H_, B_), 256, 0, stream>>>(x, xbt);
  k_mix1<<<2304, 256, 0, stream>>>(rw, W1, w1m);
  if (fused) {
    k_conv1<<<dim3(128, 2, 4), 512, 0, stream>>>(xbt, w1m, pa, xct, xsu, pooled, 0);
    k_mix2 <<<dim3(576, 4), 256, 0, stream>>>(pooled, srW, srb, W2, w2m, 0);
    k_conv2<<<dim3(128, 4), 512, 0, stream>>>(xct, xsu, w2m, pa, Wout, bout, out, 0);
  } else {
    for (int r = 0; r < R_; ++r) {
      k_conv1<<<dim3(128, 2, 1), 512, 0, stream>>>(xbt, w1m, pa, xct, 0, pooled, r);
      k_mix2 <<<dim3(576, 1), 256, 0, stream>>>(pooled, srW, srb, W2, w2m, r);
      k_conv2<<<dim3(128, 1), 512, 0, stream>>>(xct, 0, w2m, pa, Wout, bout, out, r);
    }
  }
}